// Round 1
// baseline (77.217 us; speedup 1.0000x reference)
//
#include <hip/hip_runtime.h>
#include <float.h>

// Problem constants (from reference)
#define BB  8
#define PP  16
#define LL  256     // events per path
#define MM  16      // models
#define LE  2048    // query times per path
#define TILE 512    // queries per block
#define THREADS 256

// Grid: (B*P) * (LE/TILE) blocks. Each block owns one (b,p) pair and a tile of
// 512 query times. All M=16 models' params for this (b,p) are staged in LDS
// (48 KB) since the gather index ci is random per query.
__global__ __launch_bounds__(THREADS) void hawkes_intensity_kernel(
    const float* __restrict__ qt,     // [B,P,LE]
    const float* __restrict__ ev,     // [B,P,LL] sorted ascending
    const float* __restrict__ mu,     // [B,M,P,LL]
    const float* __restrict__ alpha,  // [B,M,P,LL]
    const float* __restrict__ beta,   // [B,M,P,LL]
    float* __restrict__ out)          // [B,M,P,LE]
{
    __shared__ float ev_s[LL + 1];          // +1 sentinel for branch-free search
    __shared__ float mu_s[MM * LL];
    __shared__ float al_s[MM * LL];
    __shared__ float be_s[MM * LL];

    const int tiles_per_bp = LE / TILE;     // 4
    const int bp   = blockIdx.x / tiles_per_bp;   // 0..127
    const int tile = blockIdx.x % tiles_per_bp;
    const int b = bp / PP;
    const int p = bp % PP;
    const int t = threadIdx.x;

    // ---- stage events (256 floats) ----
    ev_s[t] = ev[bp * LL + t];              // THREADS == LL == 256
    if (t == 0) ev_s[LL] = FLT_MAX;

    // ---- stage params: 3 arrays x 4096 floats = 1024 float4 each ----
    // global offset of (b,m,p) row in float4: ((b*MM+m)*PP+p)*LL/4
    // LDS layout mu_s[m*LL + l] -> float4 index m*64 + l4 == i (identical)
    {
        const float4* mu4 = (const float4*)mu;
        const float4* al4 = (const float4*)alpha;
        const float4* be4 = (const float4*)beta;
        float4* mus4 = (float4*)mu_s;
        float4* als4 = (float4*)al_s;
        float4* bes4 = (float4*)be_s;
        #pragma unroll
        for (int i = t; i < MM * LL / 4; i += THREADS) {
            const int m  = i >> 6;          // / 64
            const int l4 = i & 63;
            const int g  = ((b * MM + m) * PP + p) * (LL / 4) + l4;
            mus4[i] = mu4[g];
            als4[i] = al4[g];
            bes4[i] = be4[g];
        }
    }
    __syncthreads();

    const int le0 = tile * TILE;
    const float* qrow = qt + bp * LE + le0;

    #pragma unroll
    for (int k = 0; k < TILE; k += THREADS) {
        const int le = le0 + k + t;
        const float q = qrow[k + t];

        // count of events strictly < q via branch-free binary search.
        // Invariant: ev_s[i] < q for i < lo; ev_s[i] >= q for i >= hi.
        // 9 iterations cover range 256; sentinel makes lo==hi a no-op.
        int lo = 0, hi = LL;
        #pragma unroll
        for (int s = 0; s < 9; ++s) {
            const int mid = (lo + hi) >> 1;
            if (ev_s[mid] < q) lo = mid + 1; else hi = mid;
        }
        const int cnt = lo;                 // events before q
        const int ci  = (cnt > 0) ? (cnt - 1) : 0;
        const float t_last = (cnt > 0) ? ev_s[ci] : 0.0f;
        const float dt = q - t_last;

        // out offset for (b, m=0, p, le)
        int o = ((b * MM) * PP + p) * LE + le;
        #pragma unroll
        for (int m = 0; m < MM; ++m) {
            const float mm = mu_s[m * LL + ci];
            const float aa = al_s[m * LL + ci];
            const float bb = be_s[m * LL + ci];
            const float e  = __expf(-bb * dt);
            const float base = mm + (aa - mm) * e;      // in [0,1)
            out[o] = __logf(1.0f + __expf(base));       // softplus, safe range
            o += PP * LE;                               // next m
        }
    }
}

extern "C" void kernel_launch(void* const* d_in, const int* in_sizes, int n_in,
                              void* d_out, int out_size, void* d_ws, size_t ws_size,
                              hipStream_t stream) {
    const float* qt    = (const float*)d_in[0];  // query_times [B,P,LE]
    const float* ev    = (const float*)d_in[1];  // event_times [B,P,LL]
    const float* mu    = (const float*)d_in[2];  // [B,M,P,LL]
    const float* alpha = (const float*)d_in[3];
    const float* beta  = (const float*)d_in[4];
    float* out = (float*)d_out;                  // [B,M,P,LE] fp32

    const int nblocks = (BB * PP) * (LE / TILE); // 512
    hawkes_intensity_kernel<<<nblocks, THREADS, 0, stream>>>(qt, ev, mu, alpha, beta, out);
}